// Round 5
// baseline (56.594 us; speedup 1.0000x reference)
//
#include <hip/hip_runtime.h>

#define LDIM 512
#define SITES (LDIM * LDIM)
#define H 16                     // rows per wave
#define WPB 4                    // waves per block
#define BLK_ROWS (H * WPB)       // 64 contiguous rows per block
#define BPB (LDIM / BLK_ROWS)    // 8 blocks per batch

__device__ __forceinline__ float spin_of(float x0, float x1) {
    // argmax tie-break: index 0 wins on equality -> spin -1
    return x1 > x0 ? 1.0f : -1.0f;
}

// Fused: strip compute + last-block-per-batch finalize.
// Block = 64 contiguous rows (4 waves x 16 rows). Each wave publishes its
// row-0 spins to LDS; bottom halos come from the sibling wave's LDS row
// (zero extra global traffic). Only the top halo row per wave (and wave 3's
// bottom) is re-read from global (cache-hot).
__global__ __launch_bounds__(256) void ising_fused(
        const float* __restrict__ x, float4* __restrict__ part,
        int* __restrict__ ctr, float* __restrict__ out) {
    const int b    = blockIdx.y;
    const int blk  = blockIdx.x;            // 0..BPB-1
    const int wave = threadIdx.x >> 6;
    const int lane = threadIdx.x & 63;
    const int r0   = blk * BLK_ROWS + wave * H;

    const float* xb = x + (size_t)b * (size_t)(SITES * 2);

    __shared__ float  spin0[WPB][LDIM];     // each wave's row-0 spins
    __shared__ float4 wred[WPB];

    float4 xv[3][4];    // 3-deep ring (dist-2 load pipeline)
    float  sp[3][8];    // rolling spins: rows i-1, i, i+1
    float  spBot[8];    // wave 3 only: block-bottom halo spins
    float  A = 0.f, Hs = 0.f, T12 = 0.f;

    #define LOADROW(row, dst)                                                  \
        {                                                                      \
            const float4* p_ =                                                 \
                (const float4*)(xb + (size_t)(row) * (LDIM * 2));              \
            _Pragma("unroll")                                                  \
            for (int q_ = 0; q_ < 4; ++q_) (dst)[q_] = p_[lane * 4 + q_];      \
        }
    #define SPINS(v, s)                                                        \
        {                                                                      \
            _Pragma("unroll")                                                  \
            for (int q_ = 0; q_ < 4; ++q_) {                                   \
                (s)[2 * q_]     = spin_of((v)[q_].x, (v)[q_].y);               \
                (s)[2 * q_ + 1] = spin_of((v)[q_].z, (v)[q_].w);               \
            }                                                                  \
        }

    // ---- prologue ----
    {
        float4 tmp[4];
        LOADROW((r0 + LDIM - 1) & (LDIM - 1), tmp);   // top halo row
        LOADROW(r0, xv[0]);
        LOADROW((r0 + 1) & (LDIM - 1), xv[1]);
        SPINS(tmp, sp[0]);
        SPINS(xv[0], sp[1]);
        #pragma unroll
        for (int k = 0; k < 8; ++k) spin0[wave][lane * 8 + k] = sp[1][k];
        if (wave == WPB - 1) {                         // block-bottom halo
            LOADROW((r0 + H) & (LDIM - 1), tmp);
            SPINS(tmp, spBot);
        }
    }
    __syncthreads();

    const int laneL = (lane + 63) & 63;
    const int laneR = (lane + 1) & 63;

    // ---- main loop ----
    #pragma unroll
    for (int i = 0; i < H; ++i) {
        if (i < H - 2) LOADROW((r0 + i + 2) & (LDIM - 1), xv[(i + 2) % 3]);

        float* sP = sp[i % 3];
        float* sC = sp[(i + 1) % 3];
        float* sN = sp[(i + 2) % 3];

        if (i < H - 1) {
            SPINS(xv[(i + 1) % 3], sN);                // load issued iter i-1
        } else if (wave == WPB - 1) {
            #pragma unroll
            for (int k = 0; k < 8; ++k) sN[k] = spBot[k];
        } else {
            #pragma unroll
            for (int k = 0; k < 8; ++k) sN[k] = spin0[wave + 1][lane * 8 + k];
        }

        const float sl = __shfl(sC[7], laneL);         // torus col wrap
        const float sr = __shfl(sC[0], laneR);

        #pragma unroll
        for (int k = 0; k < 8; ++k) {
            const float lft = (k == 0) ? sl : sC[k - 1];
            const float rgt = (k == 7) ? sr : sC[k + 1];
            const float h   = (lft + rgt) + (sP[k] + sN[k]);
            const float4 v  = xv[i % 3][k >> 1];
            const float x0  = (k & 1) ? v.z : v.x;
            const float x1  = (k & 1) ? v.w : v.y;
            A   += x0 + x1;
            Hs   = fmaf(sC[k], h, Hs);
            const float g = (sC[k] > 0.f) ? x0 : -x1;  // s(x0+x1)+(x0-x1) = 2g
            T12  = fmaf(g, h, T12);
        }
    }

    // ---- block reduction ----
    #pragma unroll
    for (int off = 32; off; off >>= 1) {
        A   += __shfl_down(A,   off);
        Hs  += __shfl_down(Hs,  off);
        T12 += __shfl_down(T12, off);
    }
    if (lane == 0) wred[wave] = make_float4(A, Hs, T12, 0.f);
    __syncthreads();

    if (threadIdx.x == 0) {
        float4 r = wred[0];
        #pragma unroll
        for (int w = 1; w < WPB; ++w) {
            float4 q = wred[w];
            r.x += q.x; r.y += q.y; r.z += q.z;
        }
        part[b * BPB + blk] = r;
        __threadfence();
        const int old = __hip_atomic_fetch_add(&ctr[b], 1, __ATOMIC_ACQ_REL,
                                               __HIP_MEMORY_SCOPE_AGENT);
        if (old == BPB - 1) {                          // last block of batch b
            __threadfence();
            float fA = 0.f, fH = 0.f, fT = 0.f;
            #pragma unroll
            for (int j = 0; j < BPB; ++j) {
                float4 q = part[b * BPB + j];
                fA += q.x; fH += q.y; fT += q.z;
            }
            out[b] = (-0.5f * fH * fA + 2.f * fT) * (1.0f / (float)SITES);
        }
    }

    #undef LOADROW
    #undef SPINS
}

extern "C" void kernel_launch(void* const* d_in, const int* in_sizes, int n_in,
                              void* d_out, int out_size, void* d_ws, size_t ws_size,
                              hipStream_t stream) {
    const float* x = (const float*)d_in[0];
    float* out = (float*)d_out;

    const int B = in_sizes[0] / (SITES * 2);

    float4* part = (float4*)d_ws;                       // B*BPB float4 = 8 KiB
    int*    ctr  = (int*)((char*)d_ws + 16384);

    // zero the per-batch arrival counters (poisoned to 0xAA before timing)
    hipMemsetAsync(ctr, 0, B * sizeof(int), stream);

    dim3 grid(BPB, B);                                  // 8 x 64 = 512 blocks
    ising_fused<<<grid, WPB * 64, 0, stream>>>(x, part, ctr, out);
}

// Round 6
// 34.695 us; speedup vs baseline: 1.6312x; 1.6312x over previous
//
#include <hip/hip_runtime.h>

#define LDIM 512
#define SITES (LDIM * LDIM)
#define H 16                     // rows per wave
#define WPB 4                    // waves per block
#define BLK_ROWS (H * WPB)       // 64 contiguous rows per block
#define BPB (LDIM / BLK_ROWS)    // 8 blocks per batch

__device__ __forceinline__ float spin_of(float x0, float x1) {
    // argmax tie-break: index 0 wins on equality -> spin -1
    return x1 > x0 ? 1.0f : -1.0f;
}

// Block = 64 contiguous rows (4 waves x 16 rows). Each wave publishes its
// row-0 spins to LDS; bottom halos come from the sibling wave's LDS row.
// Only the per-wave top halo row (and wave 3's bottom) is re-read from
// global (cache-hot). Plain partial stores — no fences, no atomics.
__global__ __launch_bounds__(256) void ising_strip(
        const float* __restrict__ x, float4* __restrict__ part) {
    const int b    = blockIdx.y;
    const int blk  = blockIdx.x;            // 0..BPB-1
    const int wave = threadIdx.x >> 6;
    const int lane = threadIdx.x & 63;
    const int r0   = blk * BLK_ROWS + wave * H;

    const float* xb = x + (size_t)b * (size_t)(SITES * 2);

    __shared__ float  spin0[WPB][LDIM];     // each wave's row-0 spins
    __shared__ float4 wred[WPB];

    float4 xv[2][4];    // ping-pong x buffers (dist-1 pipeline, round-2 proven)
    float  sp[3][8];    // rolling spins: rows i-1, i, i+1
    float  spBot[8];    // wave 3 only: block-bottom halo spins
    float  A = 0.f, Hs = 0.f, T12 = 0.f;

    #define LOADROW(row, dst)                                                  \
        {                                                                      \
            const float4* p_ =                                                 \
                (const float4*)(xb + (size_t)(row) * (LDIM * 2));              \
            _Pragma("unroll")                                                  \
            for (int q_ = 0; q_ < 4; ++q_) (dst)[q_] = p_[lane * 4 + q_];      \
        }
    #define SPINS(v, s)                                                        \
        {                                                                      \
            _Pragma("unroll")                                                  \
            for (int q_ = 0; q_ < 4; ++q_) {                                   \
                (s)[2 * q_]     = spin_of((v)[q_].x, (v)[q_].y);               \
                (s)[2 * q_ + 1] = spin_of((v)[q_].z, (v)[q_].w);               \
            }                                                                  \
        }

    // ---- prologue ----
    {
        float4 tmp[4];
        LOADROW((r0 + LDIM - 1) & (LDIM - 1), tmp);   // top halo row
        LOADROW(r0, xv[0]);
        SPINS(tmp, sp[0]);
        SPINS(xv[0], sp[1]);
        #pragma unroll
        for (int k = 0; k < 8; ++k) spin0[wave][lane * 8 + k] = sp[1][k];
        if (wave == WPB - 1) {                         // block-bottom halo
            LOADROW((r0 + H) & (LDIM - 1), tmp);
            SPINS(tmp, spBot);
        }
    }
    __syncthreads();

    const int laneL = (lane + 63) & 63;
    const int laneR = (lane + 1) & 63;

    // ---- main loop ----
    #pragma unroll
    for (int i = 0; i < H; ++i) {
        float* sP = sp[i % 3];
        float* sC = sp[(i + 1) % 3];
        float* sN = sp[(i + 2) % 3];

        if (i < H - 1) {
            LOADROW(r0 + i + 1, xv[(i + 1) & 1]);      // interior: no wrap
            SPINS(xv[(i + 1) & 1], sN);
        } else if (wave == WPB - 1) {
            #pragma unroll
            for (int k = 0; k < 8; ++k) sN[k] = spBot[k];
        } else {
            #pragma unroll
            for (int k = 0; k < 8; ++k) sN[k] = spin0[wave + 1][lane * 8 + k];
        }

        const float sl = __shfl(sC[7], laneL);         // torus col wrap
        const float sr = __shfl(sC[0], laneR);

        #pragma unroll
        for (int k = 0; k < 8; ++k) {
            const float lft = (k == 0) ? sl : sC[k - 1];
            const float rgt = (k == 7) ? sr : sC[k + 1];
            const float h   = (lft + rgt) + (sP[k] + sN[k]);
            const float4 v  = xv[i & 1][k >> 1];
            const float x0  = (k & 1) ? v.z : v.x;
            const float x1  = (k & 1) ? v.w : v.y;
            A   += x0 + x1;
            Hs   = fmaf(sC[k], h, Hs);
            const float g = (sC[k] > 0.f) ? x0 : -x1;  // s(x0+x1)+(x0-x1) = 2g
            T12  = fmaf(g, h, T12);
        }
    }

    // ---- block reduction, plain store ----
    #pragma unroll
    for (int off = 32; off; off >>= 1) {
        A   += __shfl_down(A,   off);
        Hs  += __shfl_down(Hs,  off);
        T12 += __shfl_down(T12, off);
    }
    if (lane == 0) wred[wave] = make_float4(A, Hs, T12, 0.f);
    __syncthreads();

    if (threadIdx.x == 0) {
        float4 r = wred[0];
        #pragma unroll
        for (int w = 1; w < WPB; ++w) {
            float4 q = wred[w];
            r.x += q.x; r.y += q.y; r.z += q.z;
        }
        part[b * BPB + blk] = r;
    }

    #undef LOADROW
    #undef SPINS
}

// Single tiny block: thread t -> batch t/8, partial t%8; group-of-8 shuffle
// reduce; lane j==0 applies the closed form. Reads 8 KiB total.
__global__ __launch_bounds__(512) void ising_final(
        const float4* __restrict__ part, float* __restrict__ out, int B) {
    const int t = threadIdx.x;
    const int b = t >> 3;
    if (b < B) {
        float4 v = part[t];
        float A = v.x, Hs = v.y, T12 = v.z;
        #pragma unroll
        for (int off = 4; off; off >>= 1) {
            A   += __shfl_down(A,   off);
            Hs  += __shfl_down(Hs,  off);
            T12 += __shfl_down(T12, off);
        }
        if ((t & 7) == 0)
            out[b] = (-0.5f * Hs * A + 2.f * T12) * (1.0f / (float)SITES);
    }
}

extern "C" void kernel_launch(void* const* d_in, const int* in_sizes, int n_in,
                              void* d_out, int out_size, void* d_ws, size_t ws_size,
                              hipStream_t stream) {
    const float* x = (const float*)d_in[0];
    float* out = (float*)d_out;
    float4* part = (float4*)d_ws;            // B*BPB float4 = 8 KiB for B=64

    const int B = in_sizes[0] / (SITES * 2);

    dim3 grid(BPB, B);                       // 8 x 64 = 512 blocks
    ising_strip<<<grid, WPB * 64, 0, stream>>>(x, part);
    ising_final<<<1, B * BPB, 0, stream>>>(part, out, B);
}

// Round 7
// 29.122 us; speedup vs baseline: 1.9433x; 1.1914x over previous
//
#include <hip/hip_runtime.h>

#define LDIM 512
#define SITES (LDIM * LDIM)
#define H 16                    // rows per strip (per wave)
#define STRIPS (LDIM / H)       // 32 strips per batch

__device__ __forceinline__ float spin_of(float x0, float x1) {
    // argmax tie-break: index 0 wins on equality -> spin -1
    return x1 > x0 ? 1.0f : -1.0f;
}

// One single-wave block per strip: 64 lanes x 8 cols = full 512-wide row.
// Walks H=16 rows with a 3-row rolling spin window; every row loaded once
// (+2 halo rows). 2048 independent 64-thread blocks -> fine-grained dispatch
// (8 blocks/CU), no LDS, no barriers.
__global__ __launch_bounds__(64) void ising_strip(
        const float* __restrict__ x, float4* __restrict__ part) {
    const int b     = blockIdx.y;
    const int strip = blockIdx.x;
    const int lane  = threadIdx.x;
    const int r0    = strip * H;

    const float* xb = x + (size_t)b * (size_t)(SITES * 2);

    float4 xv[2][4];   // ping-pong x buffers (row being consumed / row loading)
    float  sp[3][8];   // rolling spins: rows r-1, r, r+1
    float A = 0.f, Hs = 0.f, T12 = 0.f;

    #define LOADROW(row, dst)                                                  \
        {                                                                      \
            const float4* p_ =                                                 \
                (const float4*)(xb + (size_t)(row) * (LDIM * 2));              \
            _Pragma("unroll")                                                  \
            for (int q_ = 0; q_ < 4; ++q_) (dst)[q_] = p_[lane * 4 + q_];      \
        }
    #define SPINS(v, s)                                                        \
        {                                                                      \
            _Pragma("unroll")                                                  \
            for (int q_ = 0; q_ < 4; ++q_) {                                   \
                (s)[2 * q_]     = spin_of((v)[q_].x, (v)[q_].y);               \
                (s)[2 * q_ + 1] = spin_of((v)[q_].z, (v)[q_].w);               \
            }                                                                  \
        }

    // prologue: halo row r0-1 -> sp[0]; row r0 -> xv[0], spins -> sp[1]
    {
        float4 tmp[4];
        LOADROW((r0 + LDIM - 1) & (LDIM - 1), tmp);
        SPINS(tmp, sp[0]);
        LOADROW(r0, xv[0]);
        SPINS(xv[0], sp[1]);
    }

    const int laneL = (lane + 63) & 63;
    const int laneR = (lane + 1) & 63;

    #pragma unroll
    for (int i = 0; i < H; ++i) {
        const int cur = i & 1;          // xv slot holding row r0+i
        const int nxt = (i + 1) & 1;
        LOADROW((r0 + i + 1) & (LDIM - 1), xv[nxt]);
        float* sP = sp[i % 3];          // row r0+i-1
        float* sC = sp[(i + 1) % 3];    // row r0+i
        float* sN = sp[(i + 2) % 3];    // row r0+i+1
        SPINS(xv[nxt], sN);

        const float sl = __shfl(sC[7], laneL);  // torus col wrap (wave = row)
        const float sr = __shfl(sC[0], laneR);

        #pragma unroll
        for (int k = 0; k < 8; ++k) {
            const float lft = (k == 0) ? sl : sC[k - 1];
            const float rgt = (k == 7) ? sr : sC[k + 1];
            const float h   = (lft + rgt) + (sP[k] + sN[k]);
            const float4 v  = xv[cur][k >> 1];
            const float x0  = (k & 1) ? v.z : v.x;
            const float x1  = (k & 1) ? v.w : v.y;
            A   += x0 + x1;
            Hs   = fmaf(sC[k], h, Hs);
            const float g = (sC[k] > 0.f) ? x0 : -x1;  // s(x0+x1)+(x0-x1) = 2g
            T12  = fmaf(g, h, T12);
        }
    }

    #pragma unroll
    for (int off = 32; off; off >>= 1) {
        A   += __shfl_down(A,   off);
        Hs  += __shfl_down(Hs,  off);
        T12 += __shfl_down(T12, off);
    }
    if (lane == 0) part[b * STRIPS + strip] = make_float4(A, Hs, T12, 0.f);

    #undef LOADROW
    #undef SPINS
}

// One block (single wave) per batch: reduce STRIPS partials, apply closed form.
__global__ __launch_bounds__(64) void ising_final(
        const float4* __restrict__ part, float* __restrict__ out) {
    const int b = blockIdx.x;
    const int t = threadIdx.x;
    float A = 0.f, Hs = 0.f, T12 = 0.f;
    if (t < STRIPS) {
        float4 v = part[b * STRIPS + t];
        A = v.x; Hs = v.y; T12 = v.z;
    }
    #pragma unroll
    for (int off = 16; off; off >>= 1) {
        A   += __shfl_down(A,   off);
        Hs  += __shfl_down(Hs,  off);
        T12 += __shfl_down(T12, off);
    }
    if (t == 0) {
        out[b] = (-0.5f * Hs * A + 2.f * T12) * (1.0f / (float)SITES);
    }
}

extern "C" void kernel_launch(void* const* d_in, const int* in_sizes, int n_in,
                              void* d_out, int out_size, void* d_ws, size_t ws_size,
                              hipStream_t stream) {
    const float* x = (const float*)d_in[0];
    float* out = (float*)d_out;
    float4* part = (float4*)d_ws;   // B * STRIPS float4 partials (32 KiB for B=64)

    const int B = in_sizes[0] / (SITES * 2);

    dim3 grid(STRIPS, B);           // 32 x 64 = 2048 single-wave blocks
    ising_strip<<<grid, 64, 0, stream>>>(x, part);
    ising_final<<<B, 64, 0, stream>>>(part, out);
}

// Round 9
// 28.189 us; speedup vs baseline: 2.0077x; 1.0331x over previous
//
#include <hip/hip_runtime.h>

#define LDIM 512
#define SITES (LDIM * LDIM)
#define H 32                    // rows per strip (per wave)
#define STRIPS (LDIM / H)       // 16 strips per batch

__device__ __forceinline__ float spin_of(float x0, float x1) {
    // argmax tie-break: index 0 wins on equality -> spin -1
    return x1 > x0 ? 1.0f : -1.0f;
}

// One single-wave block per strip: 64 lanes x 8 cols = full 512-wide row.
// Walks H=32 rows with a 3-row rolling spin window and a distance-2 load
// pipeline; every row loaded once (+2 halo rows -> 1.0625x amplification).
// 1024 independent 64-thread blocks (4 waves/CU), no LDS, no barriers.
__global__ __launch_bounds__(64) void ising_strip(
        const float* __restrict__ x, float4* __restrict__ part) {
    const int b     = blockIdx.y;
    const int strip = blockIdx.x;
    const int lane  = threadIdx.x;
    const int r0    = strip * H;

    const float* xb = x + (size_t)b * (size_t)(SITES * 2);

    float4 xv[3][4];   // 3-deep ring: rows i-1 (dying), i, i+1 (landing)
    float  sp[3][8];   // rolling spins: rows i-1, i, i+1
    float A = 0.f, Hs = 0.f, T12 = 0.f;

    #define LOADROW(row, dst)                                                  \
        do {                                                                   \
            const float4* p_ =                                                 \
                (const float4*)(xb + (size_t)(row) * (LDIM * 2));              \
            _Pragma("unroll")                                                  \
            for (int q_ = 0; q_ < 4; ++q_) (dst)[q_] = p_[lane * 4 + q_];      \
        } while (0)
    #define SPINS(v, s)                                                        \
        do {                                                                   \
            _Pragma("unroll")                                                  \
            for (int q_ = 0; q_ < 4; ++q_) {                                   \
                (s)[2 * q_]     = spin_of((v)[q_].x, (v)[q_].y);               \
                (s)[2 * q_ + 1] = spin_of((v)[q_].z, (v)[q_].w);               \
            }                                                                  \
        } while (0)

    // prologue: issue halo(r0-1), row r0, row r0+1 loads; spins for first two
    {
        float4 tmp[4];
        LOADROW((r0 + LDIM - 1) & (LDIM - 1), tmp);
        LOADROW(r0, xv[0]);
        LOADROW(r0 + 1, xv[1]);            // H>=2, interior: no wrap
        SPINS(tmp, sp[0]);
        SPINS(xv[0], sp[1]);
    }

    const int laneL = (lane + 63) & 63;
    const int laneR = (lane + 1) & 63;

    #pragma unroll
    for (int i = 0; i < H; ++i) {
        // issue load of row r0+i+2 (lands one iteration from now);
        // rows r0+2 .. r0+H-1 are interior, r0+H wraps for the last strip
        if (i < H - 2)       LOADROW(r0 + i + 2, xv[(i + 2) % 3]);
        else if (i == H - 2) LOADROW((r0 + H) & (LDIM - 1), xv[(i + 2) % 3]);

        float* sP = sp[i % 3];          // row r0+i-1
        float* sC = sp[(i + 1) % 3];    // row r0+i
        float* sN = sp[(i + 2) % 3];    // row r0+i+1
        SPINS(xv[(i + 1) % 3], sN);     // consumes load issued at iter i-1

        const float sl = __shfl(sC[7], laneL);  // torus col wrap (wave = row)
        const float sr = __shfl(sC[0], laneR);

        #pragma unroll
        for (int k = 0; k < 8; ++k) {
            const float lft = (k == 0) ? sl : sC[k - 1];
            const float rgt = (k == 7) ? sr : sC[k + 1];
            const float h   = (lft + rgt) + (sP[k] + sN[k]);
            const float4 v  = xv[i % 3][k >> 1];
            const float x0  = (k & 1) ? v.z : v.x;
            const float x1  = (k & 1) ? v.w : v.y;
            A   += x0 + x1;
            Hs   = fmaf(sC[k], h, Hs);
            const float g = (sC[k] > 0.f) ? x0 : -x1;  // s(x0+x1)+(x0-x1) = 2g
            T12  = fmaf(g, h, T12);
        }
    }

    #pragma unroll
    for (int off = 32; off; off >>= 1) {
        A   += __shfl_down(A,   off);
        Hs  += __shfl_down(Hs,  off);
        T12 += __shfl_down(T12, off);
    }
    if (lane == 0) part[b * STRIPS + strip] = make_float4(A, Hs, T12, 0.f);

    #undef LOADROW
    #undef SPINS
}

// One block (single wave) per batch: reduce STRIPS partials, apply closed form.
__global__ __launch_bounds__(64) void ising_final(
        const float4* __restrict__ part, float* __restrict__ out) {
    const int b = blockIdx.x;
    const int t = threadIdx.x;
    float A = 0.f, Hs = 0.f, T12 = 0.f;
    if (t < STRIPS) {
        float4 v = part[b * STRIPS + t];
        A = v.x; Hs = v.y; T12 = v.z;
    }
    #pragma unroll
    for (int off = 8; off; off >>= 1) {
        A   += __shfl_down(A,   off);
        Hs  += __shfl_down(Hs,  off);
        T12 += __shfl_down(T12, off);
    }
    if (t == 0) {
        out[b] = (-0.5f * Hs * A + 2.f * T12) * (1.0f / (float)SITES);
    }
}

extern "C" void kernel_launch(void* const* d_in, const int* in_sizes, int n_in,
                              void* d_out, int out_size, void* d_ws, size_t ws_size,
                              hipStream_t stream) {
    const float* x = (const float*)d_in[0];
    float* out = (float*)d_out;
    float4* part = (float4*)d_ws;   // B * STRIPS float4 partials (16 KiB for B=64)

    const int B = in_sizes[0] / (SITES * 2);

    dim3 grid(STRIPS, B);           // 16 x 64 = 1024 single-wave blocks
    ising_strip<<<grid, 64, 0, stream>>>(x, part);
    ising_final<<<B, 64, 0, stream>>>(part, out);
}